// Round 18
// baseline (166.359 us; speedup 1.0000x reference)
//
#include <hip/hip_runtime.h>

// ---------- types ----------
typedef __attribute__((ext_vector_type(8))) short bf16x8;   // 8 bf16 in 4 VGPRs
typedef __attribute__((ext_vector_type(4))) float f32x4;    // MFMA accumulator 16x16
typedef __attribute__((ext_vector_type(16))) float f32x16;  // MFMA accumulator 32x32

__device__ inline f32x4 mfma16(bf16x8 a, bf16x8 b, f32x4 c) {
    return __builtin_amdgcn_mfma_f32_16x16x32_bf16(a, b, c, 0, 0, 0);
}
__device__ inline f32x16 mfma32(bf16x8 a, bf16x8 b, f32x16 c) {
    return __builtin_amdgcn_mfma_f32_32x32x16_bf16(a, b, c, 0, 0, 0);
}

__device__ inline short f2bf(float f) {
    unsigned u = __builtin_bit_cast(unsigned, f);
    unsigned r = (u + 0x7fffu + ((u >> 16) & 1u)) >> 16;   // RNE
    return (short)r;
}
__device__ inline float bf2f(short h) {
    unsigned u = ((unsigned)(unsigned short)h) << 16;
    return __builtin_bit_cast(float, u);
}

__device__ inline unsigned cvt_pk_bf16(float lo, float hi) {
    unsigned r;
    asm("v_cvt_pk_bf16_f32 %0, %1, %2" : "=v"(r) : "v"(lo), "v"(hi));
    return r;
}
__device__ inline void plane_swap(unsigned& a, unsigned& b) {
    asm("v_permlane32_swap_b32 %0, %1" : "+v"(a), "+v"(b));
}
__device__ inline float exp2_hw(float x) {
    float r;
    asm("v_exp_f32 %0, %1" : "=v"(r) : "v"(x));
    return r;
}

#define GAS(p) (const __attribute__((address_space(1))) void*)(p)
#define LAS(p) (__attribute__((address_space(3))) void*)(p)

// ---------- constants ----------
#define T_SEQ 4096
#define C_DIM 1024
#define N_HEAD 16
#define HEAD_DIM 64
// -log2(e)/8 folded into q so sigmoid(x) = rcp(1 + exp2(sv))
#define QSCALE (-0.18033688011112042f)
// 1/(sqrt(T)+1e-6) folded into wproj cast
#define INV64 (1.0f / (64.0f + 1e-6f))

// ---------- kernel 1: cast fp32 -> bf16 for x + 4 weights ----------
__global__ __launch_bounds__(256) void cast5(
    const float* __restrict__ s0, const float* __restrict__ s1,
    const float* __restrict__ s2, const float* __restrict__ s3,
    const float* __restrict__ s4,
    short* __restrict__ d0, short* __restrict__ d1, short* __restrict__ d2,
    short* __restrict__ d3, short* __restrict__ d4,
    int n0, int n1, int n2, int n3, int n4)
{
    int z = blockIdx.y;
    const float* s; short* d; int n;
    switch (z) {
        case 0: s = s0; d = d0; n = n0; break;
        case 1: s = s1; d = d1; n = n1; break;
        case 2: s = s2; d = d2; n = n2; break;
        case 3: s = s3; d = d3; n = n3; break;
        default: s = s4; d = d4; n = n4; break;
    }
    float sc = (z == 4) ? INV64 : 1.0f;
    int i = (blockIdx.x * 256 + threadIdx.x) * 4;
    if (i >= n) return;
    float4 v = *(const float4*)&s[i];
    short4 o;
    o.x = f2bf(v.x * sc); o.y = f2bf(v.y * sc);
    o.z = f2bf(v.z * sc); o.w = f2bf(v.w * sc);
    *(short4*)&d[i] = o;
}

// ---------- 2-buffer GEMM staging (counted vmcnt(4), source granule-swizzle) ----------
#define QSTAGE(t_, b_) do {                                                      \
    int k0_ = (t_) * 32;                                                         \
    _Pragma("unroll")                                                            \
    for (int s2_ = 0; s2_ < 2; s2_++) {                                          \
        int rbase_ = wave * 32 + s2_ * 16;                                       \
        __builtin_amdgcn_global_load_lds(                                        \
            GAS(&A[(size_t)(row0 + rbase_ + srow) * KK + k0_ + scolx]),          \
            LAS(&sA[b_][rbase_ * 32]), 16, 0, 0);                                \
        __builtin_amdgcn_global_load_lds(                                        \
            GAS(&B[(size_t)(col0 + rbase_ + srow) * KK + k0_ + scolx]),          \
            LAS(&sB[b_][rbase_ * 32]), 16, 0, 0);                                \
    }                                                                            \
} while (0)

// stage t+1 into buf^1, counted wait for stage t, barrier, compute t, barrier
#define GEMM_STEP2(t_, nt_, bcur_) do {                                          \
    if ((t_) + 1 < (nt_)) {                                                      \
        QSTAGE((t_) + 1, (bcur_) ^ 1);                                           \
        asm volatile("s_waitcnt vmcnt(4)" ::: "memory");                         \
    } else {                                                                     \
        asm volatile("s_waitcnt vmcnt(0)" ::: "memory");                         \
    }                                                                            \
    __builtin_amdgcn_s_barrier();                                                \
    bf16x8 af[4], bfv[4];                                                        \
    _Pragma("unroll")                                                            \
    for (int m = 0; m < 4; m++) {                                                \
        int row_ = wr * 64 + m * 16 + llo;                                       \
        af[m] = *(const bf16x8*)&sA[bcur_][row_ * 32 + ((lhi ^ (llo & 3)) * 8)]; \
    }                                                                            \
    _Pragma("unroll")                                                            \
    for (int n = 0; n < 4; n++) {                                                \
        int row_ = wc * 64 + n * 16 + llo;                                       \
        bfv[n] = *(const bf16x8*)&sB[bcur_][row_ * 32 + ((lhi ^ (llo & 3)) * 8)];\
    }                                                                            \
    __builtin_amdgcn_s_setprio(1);                                               \
    _Pragma("unroll")                                                            \
    for (int m = 0; m < 4; m++)                                                  \
        _Pragma("unroll")                                                        \
        for (int n = 0; n < 4; n++)                                              \
            acc[m][n] = mfma16(af[m], bfv[n], acc[m][n]);                        \
    __builtin_amdgcn_s_setprio(0);                                               \
    asm volatile("" ::: "memory");                                               \
    __builtin_amdgcn_s_barrier();                                                \
} while (0)

// ---------- kernel 2a: fused QKV GEMM + RoPE/RMS (q,k) + V-transpose epilogue ----------
// Grid dim3(24, 32): blockIdx.x = col0_tile + 8*z  =>  XCD = col0_tile (id&7).
// z==2 (V) writes DIRECTLY to [H][D][T] via short4 stores (vtrans fused away).
// launch_bounds (256,5): LDS 32KB allows 5 blocks/CU; VGPR 88 <= 102 so no spill.
__global__ __launch_bounds__(256, 5) void gemm_qkv(
    const short* __restrict__ A,
    const short* __restrict__ B0, const short* __restrict__ B1,
    const short* __restrict__ B2,
    short* __restrict__ qnb, short* __restrict__ knb, short* __restrict__ vtb,
    const float* __restrict__ cosT, const float* __restrict__ sinT)
{
    int xx = blockIdx.x;
    int ct = xx & 7, z = xx >> 3;
    const short* B = (z == 0) ? B0 : ((z == 1) ? B1 : B2);

    __shared__ alignas(16) short sA[2][128 * 32];
    __shared__ alignas(16) short sB[2][128 * 32];

    int tid  = threadIdx.x;
    int wave = tid >> 6, lane = tid & 63;
    int lhi  = lane >> 4, llo = lane & 15;
    int wr   = wave >> 1, wc = wave & 1;
    int row0 = blockIdx.y * 128, col0 = ct * 128;
    const int KK = C_DIM;

    int srow  = lane >> 2;
    int scolx = (((lane & 3) ^ (srow & 3)) * 8);   // source granule swizzle

    f32x4 acc[4][4];
#pragma unroll
    for (int m = 0; m < 4; m++)
#pragma unroll
        for (int n = 0; n < 4; n++)
            acc[m][n] = (f32x4){0.f, 0.f, 0.f, 0.f};

    QSTAGE(0, 0);
    int bcur = 0;
    for (int t = 0; t < 32; t++) {
        GEMM_STEP2(t, 32, bcur);
        bcur ^= 1;
    }

    // ---- epilogue: this wave's 64 cols = head hH; rows are t indices ----
    int hH = ct * 2 + wc;
    if (z < 2) {
        short* dst = z ? knb : qnb;
        float osc = z ? 1.0f : QSCALE;
#pragma unroll
        for (int m = 0; m < 4; m++)
#pragma unroll
            for (int r = 0; r < 4; r++) {
                int row = row0 + wr * 64 + m * 16 + lhi * 4 + r;   // t index
                float c0 = cosT[row * 32 + llo],      c1 = cosT[row * 32 + 16 + llo];
                float s0 = sinT[row * 32 + llo],      s1 = sinT[row * 32 + 16 + llo];
                float e0 = acc[m][0][r], e1 = acc[m][1][r];
                float e2 = acc[m][2][r], e3 = acc[m][3][r];
                float r0 = e0 * c0 + e2 * s0;
                float r1 = e1 * c1 + e3 * s1;
                float r2 = e2 * c0 - e0 * s0;
                float r3 = e3 * c1 - e1 * s1;
                float sq = r0 * r0 + r1 * r1 + r2 * r2 + r3 * r3;
                sq += __shfl_xor(sq, 1);
                sq += __shfl_xor(sq, 2);
                sq += __shfl_xor(sq, 4);
                sq += __shfl_xor(sq, 8);
                float inv = rsqrtf(sq * (1.0f / 64.0f) + 1e-6f) * osc;
                size_t base = ((size_t)hH * T_SEQ + row) * HEAD_DIM + llo;
                dst[base +  0] = f2bf(r0 * inv);
                dst[base + 16] = f2bf(r1 * inv);
                dst[base + 32] = f2bf(r2 * inv);
                dst[base + 48] = f2bf(r3 * inv);
            }
    } else {
        // V: direct transposed store to [H][D][T]; d = n*16+llo, t = row (4 consec)
#pragma unroll
        for (int m = 0; m < 4; m++)
#pragma unroll
            for (int n = 0; n < 4; n++) {
                int trow = row0 + wr * 64 + m * 16 + lhi * 4;
                short4 o;
                o.x = f2bf(acc[m][n][0]);
                o.y = f2bf(acc[m][n][1]);
                o.z = f2bf(acc[m][n][2]);
                o.w = f2bf(acc[m][n][3]);
                *(short4*)&vtb[((size_t)(hH * HEAD_DIM + n * 16 + llo)) * T_SEQ + trow] = o;
            }
    }
}

// ---------- kernel 2b: proj GEMM (fp32 out) ----------
__global__ __launch_bounds__(256, 4) void gemm_proj(
    const short* __restrict__ A, const short* __restrict__ B,
    float* __restrict__ C, int M, int N, int K)
{
    __shared__ alignas(16) short sA[2][128 * 32];
    __shared__ alignas(16) short sB[2][128 * 32];

    int tid  = threadIdx.x;
    int wave = tid >> 6, lane = tid & 63;
    int lhi  = lane >> 4, llo = lane & 15;
    int wr   = wave >> 1, wc = wave & 1;
    int row0 = blockIdx.y * 128, col0 = blockIdx.x * 128;
    const int KK = K;

    int srow  = lane >> 2;
    int scolx = (((lane & 3) ^ (srow & 3)) * 8);

    f32x4 acc[4][4];
#pragma unroll
    for (int m = 0; m < 4; m++)
#pragma unroll
        for (int n = 0; n < 4; n++)
            acc[m][n] = (f32x4){0.f, 0.f, 0.f, 0.f};

    int nt = K >> 5;
    QSTAGE(0, 0);
    int bcur = 0;
    for (int t = 0; t < nt; t++) {
        GEMM_STEP2(t, nt, bcur);
        bcur ^= 1;
    }

#pragma unroll
    for (int m = 0; m < 4; m++)
#pragma unroll
        for (int n = 0; n < 4; n++)
#pragma unroll
            for (int r = 0; r < 4; r++) {
                int row = row0 + wr * 64 + m * 16 + lhi * 4 + r;
                int col = col0 + wc * 64 + n * 16 + llo;
                C[(size_t)row * N + col] = acc[m][n][r];
            }
}

// ---------- kernel 3: attention — VERBATIM attn6 (proven 58 us) ----------
#define STAGE6(s_, bf_) do {                                                     \
    int kb_ = (s_) * 64;                                                         \
    int r_  = lane >> 3;                                                         \
    int ss_ = (lane & 7) ^ r_;                                                   \
    __builtin_amdgcn_global_load_lds(                                            \
        GAS(Kh + (size_t)(kb_ + wv * 16 + r_) * HEAD_DIM + ss_ * 8),             \
        LAS(Smem + (bf_) * 8192 + (wv * 16) * 128), 16, 0, 0);                   \
    __builtin_amdgcn_global_load_lds(                                            \
        GAS(Kh + (size_t)(kb_ + wv * 16 + 8 + r_) * HEAD_DIM + ss_ * 8),         \
        LAS(Smem + (bf_) * 8192 + (wv * 16 + 8) * 128), 16, 0, 0);               \
    __builtin_amdgcn_global_load_lds(                                            \
        GAS(Vh + (size_t)(wv * 16 + r_) * T_SEQ + kb_ + ss_ * 8),                \
        LAS(Smem + 16384 + (bf_) * 8192 + (wv * 16) * 128), 16, 0, 0);           \
    __builtin_amdgcn_global_load_lds(                                            \
        GAS(Vh + (size_t)(wv * 16 + 8 + r_) * T_SEQ + kb_ + ss_ * 8),            \
        LAS(Smem + 16384 + (bf_) * 8192 + (wv * 16 + 8) * 128), 16, 0, 0);       \
} while (0)

__global__ __launch_bounds__(256, 4) void attn6(
    const short* __restrict__ qn, const short* __restrict__ kn,
    const short* __restrict__ vt, short* __restrict__ yb)
{
    __shared__ alignas(16) char Smem[32768];   // K dbuf 16K | V dbuf 16K; Yred overlay

    int id = blockIdx.x;
    int h  = id & 15;
    int g  = id >> 4;                                // 0..63
    int t  = (g < 16) ? (63 - g) : (g < 32) ? (g - 16)
           : (g < 48) ? (79 - g) : (g - 32);         // per-CU quadruple sums const
    int ns = t + 1;                                  // 64-kv steps

    int tid = threadIdx.x, wv = tid >> 6, lane = tid & 63;
    int lo = lane & 31, hi = lane >> 5;
    int band = wv & 1, tm = wv >> 1;

    const short* Qh = qn + (size_t)h * T_SEQ * HEAD_DIM;
    const short* Kh = kn + (size_t)h * T_SEQ * HEAD_DIM;
    const short* Vh = vt + (size_t)h * HEAD_DIM * T_SEQ;

    int q0 = t * 64;
    int qrow  = q0 + band * 32 + lo;
    int qmaxw = q0 + band * 32 + 31;

    const short* Qr = &Qh[(size_t)qrow * HEAD_DIM + hi * 8];
    bf16x8 qf0 = *(const bf16x8*)&Qr[0];
    bf16x8 qf1 = *(const bf16x8*)&Qr[16];
    bf16x8 qf2 = *(const bf16x8*)&Qr[32];
    bf16x8 qf3 = *(const bf16x8*)&Qr[48];

    f32x16 zed;
#pragma unroll
    for (int r = 0; r < 16; r++) zed[r] = 0.f;

    f32x16 yac0, yac1;
#pragma unroll
    for (int r = 0; r < 16; r++) { yac0[r] = 0.f; yac1[r] = 0.f; }

    // loop-invariant LDS byte offsets (swizzled reads)
    unsigned sw   = (unsigned)((lo & 7) << 4);
    unsigned krow = (unsigned)((tm * 32 + lo) * 128);
    unsigned ko0 = krow + ((0u * 32 + hi * 16) ^ sw);
    unsigned ko1 = krow + ((1u * 32 + hi * 16) ^ sw);
    unsigned ko2 = krow + ((2u * 32 + hi * 16) ^ sw);
    unsigned ko3 = krow + ((3u * 32 + hi * 16) ^ sw);
    unsigned vrow0 = (unsigned)(lo * 128)        + 16384u;
    unsigned vrow1 = (unsigned)((32 + lo) * 128) + 16384u;
    unsigned vo00 = vrow0 + (((unsigned)(tm * 64 + 0 * 32 + hi * 16)) ^ sw);
    unsigned vo01 = vrow0 + (((unsigned)(tm * 64 + 1 * 32 + hi * 16)) ^ sw);
    unsigned vo10 = vrow1 + (((unsigned)(tm * 64 + 0 * 32 + hi * 16)) ^ sw);
    unsigned vo11 = vrow1 + (((unsigned)(tm * 64 + 1 * 32 + hi * 16)) ^ sw);

    STAGE6(0, 0);
    int buf = 0;
    for (int s = 0; s < ns; s++) {
        if (s + 1 < ns) {
            STAGE6(s + 1, buf ^ 1);
            asm volatile("s_waitcnt vmcnt(4)" ::: "memory");
        } else {
            asm volatile("s_waitcnt vmcnt(0)" ::: "memory");
        }
        __builtin_amdgcn_s_barrier();

        int kb0 = s * 64 + tm * 32;
        if (kb0 <= qmaxw) {
            const char* B_ = Smem + (buf << 13);
            bf16x8 kf0 = *(const bf16x8*)(B_ + ko0);
            bf16x8 kf1 = *(const bf16x8*)(B_ + ko1);
            bf16x8 kf2 = *(const bf16x8*)(B_ + ko2);
            bf16x8 kf3 = *(const bf16x8*)(B_ + ko3);
            bf16x8 vf00 = *(const bf16x8*)(B_ + vo00);
            bf16x8 vf01 = *(const bf16x8*)(B_ + vo01);
            bf16x8 vf10 = *(const bf16x8*)(B_ + vo10);
            bf16x8 vf11 = *(const bf16x8*)(B_ + vo11);

            f32x16 sv;
            __builtin_amdgcn_s_setprio(1);
            sv = mfma32(kf0, qf0, zed);
            sv = mfma32(kf1, qf1, sv);
            sv = mfma32(kf2, qf2, sv);
            sv = mfma32(kf3, qf3, sv);
            __builtin_amdgcn_s_setprio(0);

            if (kb0 + 31 > q0 + band * 32) {         // diagonal chunk: element mask
#pragma unroll
                for (int r = 0; r < 16; r++) {
                    int kvg = kb0 + (r & 3) + 8 * (r >> 2) + 4 * hi;
                    float pv = __builtin_amdgcn_rcpf(1.f + exp2_hw(sv[r]));
                    sv[r] = (kvg <= qrow) ? pv : 0.f;
                }
            } else {
#pragma unroll
                for (int r = 0; r < 16; r++)
                    sv[r] = __builtin_amdgcn_rcpf(1.f + exp2_hw(sv[r]));
            }

#pragma unroll
            for (int k2 = 0; k2 < 2; k2++) {
                unsigned wA = cvt_pk_bf16(sv[8 * k2 + 0], sv[8 * k2 + 1]);
                unsigned wC = cvt_pk_bf16(sv[8 * k2 + 2], sv[8 * k2 + 3]);
                unsigned wB = cvt_pk_bf16(sv[8 * k2 + 4], sv[8 * k2 + 5]);
                unsigned wD = cvt_pk_bf16(sv[8 * k2 + 6], sv[8 * k2 + 7]);
                plane_swap(wA, wB);
                plane_swap(wC, wD);
                union { unsigned u[4]; bf16x8 v; } pw;
                pw.u[0] = wA; pw.u[1] = wC; pw.u[2] = wB; pw.u[3] = wD;
                __builtin_amdgcn_s_setprio(1);
                yac0 = mfma32(pw.v, k2 ? vf01 : vf00, yac0);
                yac1 = mfma32(pw.v, k2 ? vf11 : vf10, yac1);
                __builtin_amdgcn_s_setprio(0);
            }
        }
        asm volatile("" ::: "memory");
        __builtin_amdgcn_s_barrier();
        buf ^= 1;
    }

    // ---- cross-team reduce (kv halves) + store ----
    __syncthreads();
    float* Yred = (float*)Smem;                      // [2 band][32 q][64 d] overlay
    if (tm == 1) {
#pragma unroll
        for (int d = 0; d < 2; d++)
#pragma unroll
            for (int r = 0; r < 16; r++) {
                int crow = (r & 3) + 8 * (r >> 2) + 4 * hi;
                Yred[(band * 32 + crow) * 64 + d * 32 + lo] = d ? yac1[r] : yac0[r];
            }
    }
    __syncthreads();
    if (tm == 0) {
#pragma unroll
        for (int d = 0; d < 2; d++)
#pragma unroll
            for (int r = 0; r < 16; r++) {
                int crow = (r & 3) + 8 * (r >> 2) + 4 * hi;
                float v = (d ? yac1[r] : yac0[r]) + Yred[(band * 32 + crow) * 64 + d * 32 + lo];
                yb[(size_t)(q0 + band * 32 + crow) * C_DIM + h * HEAD_DIM + d * 32 + lo] = f2bf(v);
            }
    }
}

// ---------- launch ----------
extern "C" void kernel_launch(void* const* d_in, const int* in_sizes, int n_in,
                              void* d_out, int out_size, void* d_ws, size_t ws_size,
                              hipStream_t stream)
{
    const float* x    = (const float*)d_in[0];
    const float* cosT = (const float*)d_in[1];
    const float* sinT = (const float*)d_in[2];
    const float* wq   = (const float*)d_in[3];
    const float* wk   = (const float*)d_in[4];
    const float* wv   = (const float*)d_in[5];
    const float* wp   = (const float*)d_in[6];

    char* ws = (char*)d_ws;
    const size_t MB = 1024 * 1024;
    short* xb    = (short*)(ws + 0);        // [4096][1024] bf16   8 MiB
    short* wqb   = (short*)(ws + 8  * MB);
    short* wkb   = (short*)(ws + 10 * MB);
    short* wvb   = (short*)(ws + 12 * MB);
    short* wpb   = (short*)(ws + 14 * MB);  // pre-scaled by INV64
    short* qnb   = (short*)(ws + 16 * MB);  // [16][4096][64] bf16 8 MiB
    short* knb   = (short*)(ws + 24 * MB);
    short* vtb   = (short*)(ws + 32 * MB);  // [16][64][4096] bf16 8 MiB (direct)
    short* yb    = (short*)(ws + 40 * MB);  // [4096][1024] bf16   8 MiB

    // 1. cast inputs to bf16 (wproj scaled by INV64)
    cast5<<<dim3(4096, 5, 1), 256, 0, stream>>>(
        x, wq, wk, wv, wp, xb, wqb, wkb, wvb, wpb,
        T_SEQ * C_DIM, C_DIM * C_DIM, C_DIM * C_DIM, C_DIM * C_DIM, C_DIM * C_DIM);

    // 2. fused QKV GEMM + RoPE/RMS (q,k) + direct V-transpose (128 tiles, 5/CU)
    gemm_qkv<<<dim3(24, 32, 1), 256, 0, stream>>>(
        xb, wqb, wkb, wvb, qnb, knb, vtb, cosT, sinT);

    // 3. causal sigmoid attention (attn6, proven)
    attn6<<<1024, 256, 0, stream>>>(qnb, knb, vtb, yb);

    // 4. output projection (fp32 out, col-fast grid)
    gemm_proj<<<dim3(8, 32, 1), 256, 0, stream>>>(
        yb, wpb, (float*)d_out, T_SEQ, C_DIM, C_DIM);
}

// Round 19
// 129.023 us; speedup vs baseline: 1.2894x; 1.2894x over previous
//
#include <hip/hip_runtime.h>

// ---------- types ----------
typedef __attribute__((ext_vector_type(8))) short bf16x8;   // 8 bf16 in 4 VGPRs
typedef __attribute__((ext_vector_type(4))) float f32x4;    // MFMA accumulator 16x16
typedef __attribute__((ext_vector_type(16))) float f32x16;  // MFMA accumulator 32x32

__device__ inline f32x4 mfma16(bf16x8 a, bf16x8 b, f32x4 c) {
    return __builtin_amdgcn_mfma_f32_16x16x32_bf16(a, b, c, 0, 0, 0);
}
__device__ inline f32x16 mfma32(bf16x8 a, bf16x8 b, f32x16 c) {
    return __builtin_amdgcn_mfma_f32_32x32x16_bf16(a, b, c, 0, 0, 0);
}

__device__ inline short f2bf(float f) {
    unsigned u = __builtin_bit_cast(unsigned, f);
    unsigned r = (u + 0x7fffu + ((u >> 16) & 1u)) >> 16;   // RNE
    return (short)r;
}
__device__ inline float bf2f(short h) {
    unsigned u = ((unsigned)(unsigned short)h) << 16;
    return __builtin_bit_cast(float, u);
}

__device__ inline unsigned cvt_pk_bf16(float lo, float hi) {
    unsigned r;
    asm("v_cvt_pk_bf16_f32 %0, %1, %2" : "=v"(r) : "v"(lo), "v"(hi));
    return r;
}
__device__ inline void plane_swap(unsigned& a, unsigned& b) {
    asm("v_permlane32_swap_b32 %0, %1" : "+v"(a), "+v"(b));
}
__device__ inline float exp2_hw(float x) {
    float r;
    asm("v_exp_f32 %0, %1" : "=v"(r) : "v"(x));
    return r;
}

#define GAS(p) (const __attribute__((address_space(1))) void*)(p)
#define LAS(p) (__attribute__((address_space(3))) void*)(p)

// ---------- constants ----------
#define T_SEQ 4096
#define C_DIM 1024
#define N_HEAD 16
#define HEAD_DIM 64
// -log2(e)/8 folded into q so sigmoid(x) = rcp(1 + exp2(sv))
#define QSCALE (-0.18033688011112042f)
// 1/(sqrt(T)+1e-6) folded into wproj cast
#define INV64 (1.0f / (64.0f + 1e-6f))

// ---------- kernel 1: cast fp32 -> bf16 for x + 4 weights ----------
__global__ __launch_bounds__(256) void cast5(
    const float* __restrict__ s0, const float* __restrict__ s1,
    const float* __restrict__ s2, const float* __restrict__ s3,
    const float* __restrict__ s4,
    short* __restrict__ d0, short* __restrict__ d1, short* __restrict__ d2,
    short* __restrict__ d3, short* __restrict__ d4,
    int n0, int n1, int n2, int n3, int n4)
{
    int z = blockIdx.y;
    const float* s; short* d; int n;
    switch (z) {
        case 0: s = s0; d = d0; n = n0; break;
        case 1: s = s1; d = d1; n = n1; break;
        case 2: s = s2; d = d2; n = n2; break;
        case 3: s = s3; d = d3; n = n3; break;
        default: s = s4; d = d4; n = n4; break;
    }
    float sc = (z == 4) ? INV64 : 1.0f;
    int i = (blockIdx.x * 256 + threadIdx.x) * 4;
    if (i >= n) return;
    float4 v = *(const float4*)&s[i];
    short4 o;
    o.x = f2bf(v.x * sc); o.y = f2bf(v.y * sc);
    o.z = f2bf(v.z * sc); o.w = f2bf(v.w * sc);
    *(short4*)&d[i] = o;
}

// ---------- 2-buffer GEMM staging (counted vmcnt(4), source granule-swizzle) ----------
#define QSTAGE(t_, b_) do {                                                      \
    int k0_ = (t_) * 32;                                                         \
    _Pragma("unroll")                                                            \
    for (int s2_ = 0; s2_ < 2; s2_++) {                                          \
        int rbase_ = wave * 32 + s2_ * 16;                                       \
        __builtin_amdgcn_global_load_lds(                                        \
            GAS(&A[(size_t)(row0 + rbase_ + srow) * KK + k0_ + scolx]),          \
            LAS(&sA[b_][rbase_ * 32]), 16, 0, 0);                                \
        __builtin_amdgcn_global_load_lds(                                        \
            GAS(&B[(size_t)(col0 + rbase_ + srow) * KK + k0_ + scolx]),          \
            LAS(&sB[b_][rbase_ * 32]), 16, 0, 0);                                \
    }                                                                            \
} while (0)

// stage t+1 into buf^1, counted wait for stage t, barrier, compute t, barrier
#define GEMM_STEP2(t_, nt_, bcur_) do {                                          \
    if ((t_) + 1 < (nt_)) {                                                      \
        QSTAGE((t_) + 1, (bcur_) ^ 1);                                           \
        asm volatile("s_waitcnt vmcnt(4)" ::: "memory");                         \
    } else {                                                                     \
        asm volatile("s_waitcnt vmcnt(0)" ::: "memory");                         \
    }                                                                            \
    __builtin_amdgcn_s_barrier();                                                \
    bf16x8 af[4], bfv[4];                                                        \
    _Pragma("unroll")                                                            \
    for (int m = 0; m < 4; m++) {                                                \
        int row_ = wr * 64 + m * 16 + llo;                                       \
        af[m] = *(const bf16x8*)&sA[bcur_][row_ * 32 + ((lhi ^ (llo & 3)) * 8)]; \
    }                                                                            \
    _Pragma("unroll")                                                            \
    for (int n = 0; n < 4; n++) {                                                \
        int row_ = wc * 64 + n * 16 + llo;                                       \
        bfv[n] = *(const bf16x8*)&sB[bcur_][row_ * 32 + ((lhi ^ (llo & 3)) * 8)];\
    }                                                                            \
    __builtin_amdgcn_s_setprio(1);                                               \
    _Pragma("unroll")                                                            \
    for (int m = 0; m < 4; m++)                                                  \
        _Pragma("unroll")                                                        \
        for (int n = 0; n < 4; n++)                                              \
            acc[m][n] = mfma16(af[m], bfv[n], acc[m][n]);                        \
    __builtin_amdgcn_s_setprio(0);                                               \
    asm volatile("" ::: "memory");                                               \
    __builtin_amdgcn_s_barrier();                                                \
} while (0)

// ---------- kernel 2a: fused QKV GEMM + RoPE/RMS (q,k) + V-transpose epilogue ----------
// Grid dim3(24, 32): blockIdx.x = col0_tile + 8*z  =>  XCD = col0_tile (id&7).
// z==2 (V) writes DIRECTLY to [H][D][T] via short4 stores (vtrans fused away).
__global__ __launch_bounds__(256, 4) void gemm_qkv(
    const short* __restrict__ A,
    const short* __restrict__ B0, const short* __restrict__ B1,
    const short* __restrict__ B2,
    short* __restrict__ qnb, short* __restrict__ knb, short* __restrict__ vtb,
    const float* __restrict__ cosT, const float* __restrict__ sinT)
{
    int xx = blockIdx.x;
    int ct = xx & 7, z = xx >> 3;
    const short* B = (z == 0) ? B0 : ((z == 1) ? B1 : B2);

    __shared__ alignas(16) short sA[2][128 * 32];
    __shared__ alignas(16) short sB[2][128 * 32];

    int tid  = threadIdx.x;
    int wave = tid >> 6, lane = tid & 63;
    int lhi  = lane >> 4, llo = lane & 15;
    int wr   = wave >> 1, wc = wave & 1;
    int row0 = blockIdx.y * 128, col0 = ct * 128;
    const int KK = C_DIM;

    int srow  = lane >> 2;
    int scolx = (((lane & 3) ^ (srow & 3)) * 8);   // source granule swizzle

    f32x4 acc[4][4];
#pragma unroll
    for (int m = 0; m < 4; m++)
#pragma unroll
        for (int n = 0; n < 4; n++)
            acc[m][n] = (f32x4){0.f, 0.f, 0.f, 0.f};

    QSTAGE(0, 0);
    int bcur = 0;
    for (int t = 0; t < 32; t++) {
        GEMM_STEP2(t, 32, bcur);
        bcur ^= 1;
    }

    // ---- epilogue: this wave's 64 cols = head hH; rows are t indices ----
    int hH = ct * 2 + wc;
    if (z < 2) {
        short* dst = z ? knb : qnb;
        float osc = z ? 1.0f : QSCALE;
#pragma unroll
        for (int m = 0; m < 4; m++)
#pragma unroll
            for (int r = 0; r < 4; r++) {
                int row = row0 + wr * 64 + m * 16 + lhi * 4 + r;   // t index
                float c0 = cosT[row * 32 + llo],      c1 = cosT[row * 32 + 16 + llo];
                float s0 = sinT[row * 32 + llo],      s1 = sinT[row * 32 + 16 + llo];
                float e0 = acc[m][0][r], e1 = acc[m][1][r];
                float e2 = acc[m][2][r], e3 = acc[m][3][r];
                float r0 = e0 * c0 + e2 * s0;
                float r1 = e1 * c1 + e3 * s1;
                float r2 = e2 * c0 - e0 * s0;
                float r3 = e3 * c1 - e1 * s1;
                float sq = r0 * r0 + r1 * r1 + r2 * r2 + r3 * r3;
                sq += __shfl_xor(sq, 1);
                sq += __shfl_xor(sq, 2);
                sq += __shfl_xor(sq, 4);
                sq += __shfl_xor(sq, 8);
                float inv = rsqrtf(sq * (1.0f / 64.0f) + 1e-6f) * osc;
                size_t base = ((size_t)hH * T_SEQ + row) * HEAD_DIM + llo;
                dst[base +  0] = f2bf(r0 * inv);
                dst[base + 16] = f2bf(r1 * inv);
                dst[base + 32] = f2bf(r2 * inv);
                dst[base + 48] = f2bf(r3 * inv);
            }
    } else {
        // V: direct transposed store to [H][D][T]; d = n*16+llo, t = row (4 consec)
#pragma unroll
        for (int m = 0; m < 4; m++)
#pragma unroll
            for (int n = 0; n < 4; n++) {
                int trow = row0 + wr * 64 + m * 16 + lhi * 4;
                short4 o;
                o.x = f2bf(acc[m][n][0]);
                o.y = f2bf(acc[m][n][1]);
                o.z = f2bf(acc[m][n][2]);
                o.w = f2bf(acc[m][n][3]);
                *(short4*)&vtb[((size_t)(hH * HEAD_DIM + n * 16 + llo)) * T_SEQ + trow] = o;
            }
    }
}

// ---------- kernel 2b: proj GEMM (fp32 out) ----------
__global__ __launch_bounds__(256, 4) void gemm_proj(
    const short* __restrict__ A, const short* __restrict__ B,
    float* __restrict__ C, int M, int N, int K)
{
    __shared__ alignas(16) short sA[2][128 * 32];
    __shared__ alignas(16) short sB[2][128 * 32];

    int tid  = threadIdx.x;
    int wave = tid >> 6, lane = tid & 63;
    int lhi  = lane >> 4, llo = lane & 15;
    int wr   = wave >> 1, wc = wave & 1;
    int row0 = blockIdx.y * 128, col0 = blockIdx.x * 128;
    const int KK = K;

    int srow  = lane >> 2;
    int scolx = (((lane & 3) ^ (srow & 3)) * 8);

    f32x4 acc[4][4];
#pragma unroll
    for (int m = 0; m < 4; m++)
#pragma unroll
        for (int n = 0; n < 4; n++)
            acc[m][n] = (f32x4){0.f, 0.f, 0.f, 0.f};

    int nt = K >> 5;
    QSTAGE(0, 0);
    int bcur = 0;
    for (int t = 0; t < nt; t++) {
        GEMM_STEP2(t, nt, bcur);
        bcur ^= 1;
    }

#pragma unroll
    for (int m = 0; m < 4; m++)
#pragma unroll
        for (int n = 0; n < 4; n++)
#pragma unroll
            for (int r = 0; r < 4; r++) {
                int row = row0 + wr * 64 + m * 16 + lhi * 4 + r;
                int col = col0 + wc * 64 + n * 16 + llo;
                C[(size_t)row * N + col] = acc[m][n][r];
            }
}

// ---------- kernel 3: attention — VERBATIM attn6 (proven 58 us) ----------
#define STAGE6(s_, bf_) do {                                                     \
    int kb_ = (s_) * 64;                                                         \
    int r_  = lane >> 3;                                                         \
    int ss_ = (lane & 7) ^ r_;                                                   \
    __builtin_amdgcn_global_load_lds(                                            \
        GAS(Kh + (size_t)(kb_ + wv * 16 + r_) * HEAD_DIM + ss_ * 8),             \
        LAS(Smem + (bf_) * 8192 + (wv * 16) * 128), 16, 0, 0);                   \
    __builtin_amdgcn_global_load_lds(                                            \
        GAS(Kh + (size_t)(kb_ + wv * 16 + 8 + r_) * HEAD_DIM + ss_ * 8),         \
        LAS(Smem + (bf_) * 8192 + (wv * 16 + 8) * 128), 16, 0, 0);               \
    __builtin_amdgcn_global_load_lds(                                            \
        GAS(Vh + (size_t)(wv * 16 + r_) * T_SEQ + kb_ + ss_ * 8),                \
        LAS(Smem + 16384 + (bf_) * 8192 + (wv * 16) * 128), 16, 0, 0);           \
    __builtin_amdgcn_global_load_lds(                                            \
        GAS(Vh + (size_t)(wv * 16 + 8 + r_) * T_SEQ + kb_ + ss_ * 8),            \
        LAS(Smem + 16384 + (bf_) * 8192 + (wv * 16 + 8) * 128), 16, 0, 0);       \
} while (0)

__global__ __launch_bounds__(256, 4) void attn6(
    const short* __restrict__ qn, const short* __restrict__ kn,
    const short* __restrict__ vt, short* __restrict__ yb)
{
    __shared__ alignas(16) char Smem[32768];   // K dbuf 16K | V dbuf 16K; Yred overlay

    int id = blockIdx.x;
    int h  = id & 15;
    int g  = id >> 4;                                // 0..63
    int t  = (g < 16) ? (63 - g) : (g < 32) ? (g - 16)
           : (g < 48) ? (79 - g) : (g - 32);         // per-CU quadruple sums const
    int ns = t + 1;                                  // 64-kv steps

    int tid = threadIdx.x, wv = tid >> 6, lane = tid & 63;
    int lo = lane & 31, hi = lane >> 5;
    int band = wv & 1, tm = wv >> 1;

    const short* Qh = qn + (size_t)h * T_SEQ * HEAD_DIM;
    const short* Kh = kn + (size_t)h * T_SEQ * HEAD_DIM;
    const short* Vh = vt + (size_t)h * HEAD_DIM * T_SEQ;

    int q0 = t * 64;
    int qrow  = q0 + band * 32 + lo;
    int qmaxw = q0 + band * 32 + 31;

    const short* Qr = &Qh[(size_t)qrow * HEAD_DIM + hi * 8];
    bf16x8 qf0 = *(const bf16x8*)&Qr[0];
    bf16x8 qf1 = *(const bf16x8*)&Qr[16];
    bf16x8 qf2 = *(const bf16x8*)&Qr[32];
    bf16x8 qf3 = *(const bf16x8*)&Qr[48];

    f32x16 zed;
#pragma unroll
    for (int r = 0; r < 16; r++) zed[r] = 0.f;

    f32x16 yac0, yac1;
#pragma unroll
    for (int r = 0; r < 16; r++) { yac0[r] = 0.f; yac1[r] = 0.f; }

    // loop-invariant LDS byte offsets (swizzled reads)
    unsigned sw   = (unsigned)((lo & 7) << 4);
    unsigned krow = (unsigned)((tm * 32 + lo) * 128);
    unsigned ko0 = krow + ((0u * 32 + hi * 16) ^ sw);
    unsigned ko1 = krow + ((1u * 32 + hi * 16) ^ sw);
    unsigned ko2 = krow + ((2u * 32 + hi * 16) ^ sw);
    unsigned ko3 = krow + ((3u * 32 + hi * 16) ^ sw);
    unsigned vrow0 = (unsigned)(lo * 128)        + 16384u;
    unsigned vrow1 = (unsigned)((32 + lo) * 128) + 16384u;
    unsigned vo00 = vrow0 + (((unsigned)(tm * 64 + 0 * 32 + hi * 16)) ^ sw);
    unsigned vo01 = vrow0 + (((unsigned)(tm * 64 + 1 * 32 + hi * 16)) ^ sw);
    unsigned vo10 = vrow1 + (((unsigned)(tm * 64 + 0 * 32 + hi * 16)) ^ sw);
    unsigned vo11 = vrow1 + (((unsigned)(tm * 64 + 1 * 32 + hi * 16)) ^ sw);

    STAGE6(0, 0);
    int buf = 0;
    for (int s = 0; s < ns; s++) {
        if (s + 1 < ns) {
            STAGE6(s + 1, buf ^ 1);
            asm volatile("s_waitcnt vmcnt(4)" ::: "memory");
        } else {
            asm volatile("s_waitcnt vmcnt(0)" ::: "memory");
        }
        __builtin_amdgcn_s_barrier();

        int kb0 = s * 64 + tm * 32;
        if (kb0 <= qmaxw) {
            const char* B_ = Smem + (buf << 13);
            bf16x8 kf0 = *(const bf16x8*)(B_ + ko0);
            bf16x8 kf1 = *(const bf16x8*)(B_ + ko1);
            bf16x8 kf2 = *(const bf16x8*)(B_ + ko2);
            bf16x8 kf3 = *(const bf16x8*)(B_ + ko3);
            bf16x8 vf00 = *(const bf16x8*)(B_ + vo00);
            bf16x8 vf01 = *(const bf16x8*)(B_ + vo01);
            bf16x8 vf10 = *(const bf16x8*)(B_ + vo10);
            bf16x8 vf11 = *(const bf16x8*)(B_ + vo11);

            f32x16 sv;
            __builtin_amdgcn_s_setprio(1);
            sv = mfma32(kf0, qf0, zed);
            sv = mfma32(kf1, qf1, sv);
            sv = mfma32(kf2, qf2, sv);
            sv = mfma32(kf3, qf3, sv);
            __builtin_amdgcn_s_setprio(0);

            if (kb0 + 31 > q0 + band * 32) {         // diagonal chunk: element mask
#pragma unroll
                for (int r = 0; r < 16; r++) {
                    int kvg = kb0 + (r & 3) + 8 * (r >> 2) + 4 * hi;
                    float pv = __builtin_amdgcn_rcpf(1.f + exp2_hw(sv[r]));
                    sv[r] = (kvg <= qrow) ? pv : 0.f;
                }
            } else {
#pragma unroll
                for (int r = 0; r < 16; r++)
                    sv[r] = __builtin_amdgcn_rcpf(1.f + exp2_hw(sv[r]));
            }

#pragma unroll
            for (int k2 = 0; k2 < 2; k2++) {
                unsigned wA = cvt_pk_bf16(sv[8 * k2 + 0], sv[8 * k2 + 1]);
                unsigned wC = cvt_pk_bf16(sv[8 * k2 + 2], sv[8 * k2 + 3]);
                unsigned wB = cvt_pk_bf16(sv[8 * k2 + 4], sv[8 * k2 + 5]);
                unsigned wD = cvt_pk_bf16(sv[8 * k2 + 6], sv[8 * k2 + 7]);
                plane_swap(wA, wB);
                plane_swap(wC, wD);
                union { unsigned u[4]; bf16x8 v; } pw;
                pw.u[0] = wA; pw.u[1] = wC; pw.u[2] = wB; pw.u[3] = wD;
                __builtin_amdgcn_s_setprio(1);
                yac0 = mfma32(pw.v, k2 ? vf01 : vf00, yac0);
                yac1 = mfma32(pw.v, k2 ? vf11 : vf10, yac1);
                __builtin_amdgcn_s_setprio(0);
            }
        }
        asm volatile("" ::: "memory");
        __builtin_amdgcn_s_barrier();
        buf ^= 1;
    }

    // ---- cross-team reduce (kv halves) + store ----
    __syncthreads();
    float* Yred = (float*)Smem;                      // [2 band][32 q][64 d] overlay
    if (tm == 1) {
#pragma unroll
        for (int d = 0; d < 2; d++)
#pragma unroll
            for (int r = 0; r < 16; r++) {
                int crow = (r & 3) + 8 * (r >> 2) + 4 * hi;
                Yred[(band * 32 + crow) * 64 + d * 32 + lo] = d ? yac1[r] : yac0[r];
            }
    }
    __syncthreads();
    if (tm == 0) {
#pragma unroll
        for (int d = 0; d < 2; d++)
#pragma unroll
            for (int r = 0; r < 16; r++) {
                int crow = (r & 3) + 8 * (r >> 2) + 4 * hi;
                float v = (d ? yac1[r] : yac0[r]) + Yred[(band * 32 + crow) * 64 + d * 32 + lo];
                yb[(size_t)(q0 + band * 32 + crow) * C_DIM + h * HEAD_DIM + d * 32 + lo] = f2bf(v);
            }
    }
}

// ---------- launch ----------
extern "C" void kernel_launch(void* const* d_in, const int* in_sizes, int n_in,
                              void* d_out, int out_size, void* d_ws, size_t ws_size,
                              hipStream_t stream)
{
    const float* x    = (const float*)d_in[0];
    const float* cosT = (const float*)d_in[1];
    const float* sinT = (const float*)d_in[2];
    const float* wq   = (const float*)d_in[3];
    const float* wk   = (const float*)d_in[4];
    const float* wv   = (const float*)d_in[5];
    const float* wp   = (const float*)d_in[6];

    char* ws = (char*)d_ws;
    const size_t MB = 1024 * 1024;
    short* xb    = (short*)(ws + 0);        // [4096][1024] bf16   8 MiB
    short* wqb   = (short*)(ws + 8  * MB);
    short* wkb   = (short*)(ws + 10 * MB);
    short* wvb   = (short*)(ws + 12 * MB);
    short* wpb   = (short*)(ws + 14 * MB);  // pre-scaled by INV64
    short* qnb   = (short*)(ws + 16 * MB);  // [16][4096][64] bf16 8 MiB
    short* knb   = (short*)(ws + 24 * MB);
    short* vtb   = (short*)(ws + 32 * MB);  // [16][64][4096] bf16 8 MiB (direct)
    short* yb    = (short*)(ws + 40 * MB);  // [4096][1024] bf16   8 MiB

    // 1. cast inputs to bf16 (wproj scaled by INV64)
    cast5<<<dim3(4096, 5, 1), 256, 0, stream>>>(
        x, wq, wk, wv, wp, xb, wqb, wkb, wvb, wpb,
        T_SEQ * C_DIM, C_DIM * C_DIM, C_DIM * C_DIM, C_DIM * C_DIM, C_DIM * C_DIM);

    // 2. fused QKV GEMM + RoPE/RMS (q,k) + direct V-transpose (vtrans fused)
    gemm_qkv<<<dim3(24, 32, 1), 256, 0, stream>>>(
        xb, wqb, wkb, wvb, qnb, knb, vtb, cosT, sinT);

    // 3. causal sigmoid attention (attn6, proven)
    attn6<<<1024, 256, 0, stream>>>(qnb, knb, vtb, yb);

    // 4. output projection (fp32 out, col-fast grid)
    gemm_proj<<<dim3(8, 32, 1), 256, 0, stream>>>(
        yb, wpb, (float*)d_out, T_SEQ, C_DIM, C_DIM);
}

// Round 20
// 128.870 us; speedup vs baseline: 1.2909x; 1.0012x over previous
//
#include <hip/hip_runtime.h>

// ---------- types ----------
typedef __attribute__((ext_vector_type(8))) short bf16x8;   // 8 bf16 in 4 VGPRs
typedef __attribute__((ext_vector_type(4))) float f32x4;    // MFMA accumulator 16x16
typedef __attribute__((ext_vector_type(16))) float f32x16;  // MFMA accumulator 32x32

__device__ inline f32x4 mfma16(bf16x8 a, bf16x8 b, f32x4 c) {
    return __builtin_amdgcn_mfma_f32_16x16x32_bf16(a, b, c, 0, 0, 0);
}
__device__ inline f32x16 mfma32(bf16x8 a, bf16x8 b, f32x16 c) {
    return __builtin_amdgcn_mfma_f32_32x32x16_bf16(a, b, c, 0, 0, 0);
}

__device__ inline short f2bf(float f) {
    unsigned u = __builtin_bit_cast(unsigned, f);
    unsigned r = (u + 0x7fffu + ((u >> 16) & 1u)) >> 16;   // RNE
    return (short)r;
}
__device__ inline float bf2f(short h) {
    unsigned u = ((unsigned)(unsigned short)h) << 16;
    return __builtin_bit_cast(float, u);
}

__device__ inline unsigned cvt_pk_bf16(float lo, float hi) {
    unsigned r;
    asm("v_cvt_pk_bf16_f32 %0, %1, %2" : "=v"(r) : "v"(lo), "v"(hi));
    return r;
}
__device__ inline void plane_swap(unsigned& a, unsigned& b) {
    asm("v_permlane32_swap_b32 %0, %1" : "+v"(a), "+v"(b));
}
__device__ inline float exp2_hw(float x) {
    float r;
    asm("v_exp_f32 %0, %1" : "=v"(r) : "v"(x));
    return r;
}

#define GAS(p) (const __attribute__((address_space(1))) void*)(p)
#define LAS(p) (__attribute__((address_space(3))) void*)(p)

// ---------- constants ----------
#define T_SEQ 4096
#define C_DIM 1024
#define N_HEAD 16
#define HEAD_DIM 64
// -log2(e)/8 folded into q so sigmoid(x) = rcp(1 + exp2(sv))
#define QSCALE (-0.18033688011112042f)
// 1/(sqrt(T)+1e-6) folded into wproj cast
#define INV64 (1.0f / (64.0f + 1e-6f))

// ---------- kernel 1: cast fp32 -> bf16 for x + 4 weights ----------
__global__ __launch_bounds__(256) void cast5(
    const float* __restrict__ s0, const float* __restrict__ s1,
    const float* __restrict__ s2, const float* __restrict__ s3,
    const float* __restrict__ s4,
    short* __restrict__ d0, short* __restrict__ d1, short* __restrict__ d2,
    short* __restrict__ d3, short* __restrict__ d4,
    int n0, int n1, int n2, int n3, int n4)
{
    int z = blockIdx.y;
    const float* s; short* d; int n;
    switch (z) {
        case 0: s = s0; d = d0; n = n0; break;
        case 1: s = s1; d = d1; n = n1; break;
        case 2: s = s2; d = d2; n = n2; break;
        case 3: s = s3; d = d3; n = n3; break;
        default: s = s4; d = d4; n = n4; break;
    }
    float sc = (z == 4) ? INV64 : 1.0f;
    int i = (blockIdx.x * 256 + threadIdx.x) * 4;
    if (i >= n) return;
    float4 v = *(const float4*)&s[i];
    short4 o;
    o.x = f2bf(v.x * sc); o.y = f2bf(v.y * sc);
    o.z = f2bf(v.z * sc); o.w = f2bf(v.w * sc);
    *(short4*)&d[i] = o;
}

// ---------- 2-buffer GEMM staging (counted vmcnt(4), source granule-swizzle) ----------
#define QSTAGE(t_, b_) do {                                                      \
    int k0_ = (t_) * 32;                                                         \
    _Pragma("unroll")                                                            \
    for (int s2_ = 0; s2_ < 2; s2_++) {                                          \
        int rbase_ = wave * 32 + s2_ * 16;                                       \
        __builtin_amdgcn_global_load_lds(                                        \
            GAS(&A[(size_t)(row0 + rbase_ + srow) * KK + k0_ + scolx]),          \
            LAS(&sA[b_][rbase_ * 32]), 16, 0, 0);                                \
        __builtin_amdgcn_global_load_lds(                                        \
            GAS(&B[(size_t)(col0 + rbase_ + srow) * KK + k0_ + scolx]),          \
            LAS(&sB[b_][rbase_ * 32]), 16, 0, 0);                                \
    }                                                                            \
} while (0)

// stage t+1 into buf^1, counted wait for stage t, barrier, compute t, barrier
#define GEMM_STEP2(t_, nt_, bcur_) do {                                          \
    if ((t_) + 1 < (nt_)) {                                                      \
        QSTAGE((t_) + 1, (bcur_) ^ 1);                                           \
        asm volatile("s_waitcnt vmcnt(4)" ::: "memory");                         \
    } else {                                                                     \
        asm volatile("s_waitcnt vmcnt(0)" ::: "memory");                         \
    }                                                                            \
    __builtin_amdgcn_s_barrier();                                                \
    bf16x8 af[4], bfv[4];                                                        \
    _Pragma("unroll")                                                            \
    for (int m = 0; m < 4; m++) {                                                \
        int row_ = wr * 64 + m * 16 + llo;                                       \
        af[m] = *(const bf16x8*)&sA[bcur_][row_ * 32 + ((lhi ^ (llo & 3)) * 8)]; \
    }                                                                            \
    _Pragma("unroll")                                                            \
    for (int n = 0; n < 4; n++) {                                                \
        int row_ = wc * 64 + n * 16 + llo;                                       \
        bfv[n] = *(const bf16x8*)&sB[bcur_][row_ * 32 + ((lhi ^ (llo & 3)) * 8)];\
    }                                                                            \
    __builtin_amdgcn_s_setprio(1);                                               \
    _Pragma("unroll")                                                            \
    for (int m = 0; m < 4; m++)                                                  \
        _Pragma("unroll")                                                        \
        for (int n = 0; n < 4; n++)                                              \
            acc[m][n] = mfma16(af[m], bfv[n], acc[m][n]);                        \
    __builtin_amdgcn_s_setprio(0);                                               \
    asm volatile("" ::: "memory");                                               \
    __builtin_amdgcn_s_barrier();                                                \
} while (0)

// ---------- kernel 2a: fused QKV GEMM + RoPE/RMS (q,k) + V-transpose epilogue ----------
// Grid dim3(24, 32): blockIdx.x = col0_tile + 8*z  =>  XCD = col0_tile (id&7).
// z==2 (V) writes DIRECTLY to [H][D][T] via short4 stores (vtrans fused away).
__global__ __launch_bounds__(256, 4) void gemm_qkv(
    const short* __restrict__ A,
    const short* __restrict__ B0, const short* __restrict__ B1,
    const short* __restrict__ B2,
    short* __restrict__ qnb, short* __restrict__ knb, short* __restrict__ vtb,
    const float* __restrict__ cosT, const float* __restrict__ sinT)
{
    int xx = blockIdx.x;
    int ct = xx & 7, z = xx >> 3;
    const short* B = (z == 0) ? B0 : ((z == 1) ? B1 : B2);

    __shared__ alignas(16) short sA[2][128 * 32];
    __shared__ alignas(16) short sB[2][128 * 32];

    int tid  = threadIdx.x;
    int wave = tid >> 6, lane = tid & 63;
    int lhi  = lane >> 4, llo = lane & 15;
    int wr   = wave >> 1, wc = wave & 1;
    int row0 = blockIdx.y * 128, col0 = ct * 128;
    const int KK = C_DIM;

    int srow  = lane >> 2;
    int scolx = (((lane & 3) ^ (srow & 3)) * 8);   // source granule swizzle

    f32x4 acc[4][4];
#pragma unroll
    for (int m = 0; m < 4; m++)
#pragma unroll
        for (int n = 0; n < 4; n++)
            acc[m][n] = (f32x4){0.f, 0.f, 0.f, 0.f};

    QSTAGE(0, 0);
    int bcur = 0;
    for (int t = 0; t < 32; t++) {
        GEMM_STEP2(t, 32, bcur);
        bcur ^= 1;
    }

    // ---- epilogue: this wave's 64 cols = head hH; rows are t indices ----
    int hH = ct * 2 + wc;
    if (z < 2) {
        short* dst = z ? knb : qnb;
        float osc = z ? 1.0f : QSCALE;
#pragma unroll
        for (int m = 0; m < 4; m++)
#pragma unroll
            for (int r = 0; r < 4; r++) {
                int row = row0 + wr * 64 + m * 16 + lhi * 4 + r;   // t index
                float c0 = cosT[row * 32 + llo],      c1 = cosT[row * 32 + 16 + llo];
                float s0 = sinT[row * 32 + llo],      s1 = sinT[row * 32 + 16 + llo];
                float e0 = acc[m][0][r], e1 = acc[m][1][r];
                float e2 = acc[m][2][r], e3 = acc[m][3][r];
                float r0 = e0 * c0 + e2 * s0;
                float r1 = e1 * c1 + e3 * s1;
                float r2 = e2 * c0 - e0 * s0;
                float r3 = e3 * c1 - e1 * s1;
                float sq = r0 * r0 + r1 * r1 + r2 * r2 + r3 * r3;
                sq += __shfl_xor(sq, 1);
                sq += __shfl_xor(sq, 2);
                sq += __shfl_xor(sq, 4);
                sq += __shfl_xor(sq, 8);
                float inv = rsqrtf(sq * (1.0f / 64.0f) + 1e-6f) * osc;
                size_t base = ((size_t)hH * T_SEQ + row) * HEAD_DIM + llo;
                dst[base +  0] = f2bf(r0 * inv);
                dst[base + 16] = f2bf(r1 * inv);
                dst[base + 32] = f2bf(r2 * inv);
                dst[base + 48] = f2bf(r3 * inv);
            }
    } else {
        // V: direct transposed store to [H][D][T]; d = n*16+llo, t = row (4 consec)
#pragma unroll
        for (int m = 0; m < 4; m++)
#pragma unroll
            for (int n = 0; n < 4; n++) {
                int trow = row0 + wr * 64 + m * 16 + lhi * 4;
                short4 o;
                o.x = f2bf(acc[m][n][0]);
                o.y = f2bf(acc[m][n][1]);
                o.z = f2bf(acc[m][n][2]);
                o.w = f2bf(acc[m][n][3]);
                *(short4*)&vtb[((size_t)(hH * HEAD_DIM + n * 16 + llo)) * T_SEQ + trow] = o;
            }
    }
}

// ---------- kernel 2b: proj GEMM (fp32 out) ----------
__global__ __launch_bounds__(256, 4) void gemm_proj(
    const short* __restrict__ A, const short* __restrict__ B,
    float* __restrict__ C, int M, int N, int K)
{
    __shared__ alignas(16) short sA[2][128 * 32];
    __shared__ alignas(16) short sB[2][128 * 32];

    int tid  = threadIdx.x;
    int wave = tid >> 6, lane = tid & 63;
    int lhi  = lane >> 4, llo = lane & 15;
    int wr   = wave >> 1, wc = wave & 1;
    int row0 = blockIdx.y * 128, col0 = blockIdx.x * 128;
    const int KK = K;

    int srow  = lane >> 2;
    int scolx = (((lane & 3) ^ (srow & 3)) * 8);

    f32x4 acc[4][4];
#pragma unroll
    for (int m = 0; m < 4; m++)
#pragma unroll
        for (int n = 0; n < 4; n++)
            acc[m][n] = (f32x4){0.f, 0.f, 0.f, 0.f};

    int nt = K >> 5;
    QSTAGE(0, 0);
    int bcur = 0;
    for (int t = 0; t < nt; t++) {
        GEMM_STEP2(t, nt, bcur);
        bcur ^= 1;
    }

#pragma unroll
    for (int m = 0; m < 4; m++)
#pragma unroll
        for (int n = 0; n < 4; n++)
#pragma unroll
            for (int r = 0; r < 4; r++) {
                int row = row0 + wr * 64 + m * 16 + lhi * 4 + r;
                int col = col0 + wc * 64 + n * 16 + llo;
                C[(size_t)row * N + col] = acc[m][n][r];
            }
}

// ---------- kernel 3: attention — 3-buffer, ONE barrier/step, stage-after-barrier ----
// Safety: stage(s+2) into buf (s+2)%3 is issued AFTER the step-s barrier; that
// buffer was last read in compute(s-1), which all waves completed before this
// barrier. Counted vmcnt(8) leaves stage(s+1)'s 8 loads in flight (2-step slack).
// LDS 48 KB -> 3 blocks/CU; everything else identical to attn6.

#define STAGE20(s_, bf_) do {                                                    \
    int kb_ = (s_) * 64;                                                         \
    int r_  = lane >> 3;                                                         \
    int ss_ = (lane & 7) ^ r_;                                                   \
    __builtin_amdgcn_global_load_lds(                                            \
        GAS(Kh + (size_t)(kb_ + wv * 16 + r_) * HEAD_DIM + ss_ * 8),             \
        LAS(Smem + (bf_) * 8192 + (wv * 16) * 128), 16, 0, 0);                   \
    __builtin_amdgcn_global_load_lds(                                            \
        GAS(Kh + (size_t)(kb_ + wv * 16 + 8 + r_) * HEAD_DIM + ss_ * 8),         \
        LAS(Smem + (bf_) * 8192 + (wv * 16 + 8) * 128), 16, 0, 0);               \
    __builtin_amdgcn_global_load_lds(                                            \
        GAS(Vh + (size_t)(wv * 16 + r_) * T_SEQ + kb_ + ss_ * 8),                \
        LAS(Smem + 24576 + (bf_) * 8192 + (wv * 16) * 128), 16, 0, 0);           \
    __builtin_amdgcn_global_load_lds(                                            \
        GAS(Vh + (size_t)(wv * 16 + 8 + r_) * T_SEQ + kb_ + ss_ * 8),            \
        LAS(Smem + 24576 + (bf_) * 8192 + (wv * 16 + 8) * 128), 16, 0, 0);       \
} while (0)

#define ASTEP(b_, bn_) {                                                         \
    if (s + 1 < ns) { asm volatile("s_waitcnt vmcnt(8)" ::: "memory"); }         \
    else            { asm volatile("s_waitcnt vmcnt(0)" ::: "memory"); }         \
    __builtin_amdgcn_s_barrier();                                                \
    if (s + 2 < ns) STAGE20(s + 2, bn_);                                         \
    int kb0 = s * 64 + tm * 32;                                                  \
    if (kb0 <= qmaxw) {                                                          \
        const char* KB_ = Smem + (b_) * 8192;                                    \
        const char* VB_ = Smem + 24576 + (b_) * 8192;                            \
        bf16x8 kf0 = *(const bf16x8*)(KB_ + ko0);                                \
        bf16x8 kf1 = *(const bf16x8*)(KB_ + ko1);                                \
        bf16x8 kf2 = *(const bf16x8*)(KB_ + ko2);                                \
        bf16x8 kf3 = *(const bf16x8*)(KB_ + ko3);                                \
        bf16x8 vf00 = *(const bf16x8*)(VB_ + vo00);                              \
        bf16x8 vf01 = *(const bf16x8*)(VB_ + vo01);                              \
        bf16x8 vf10 = *(const bf16x8*)(VB_ + vo10);                              \
        bf16x8 vf11 = *(const bf16x8*)(VB_ + vo11);                              \
        f32x16 sv;                                                               \
        __builtin_amdgcn_s_setprio(1);                                           \
        sv = mfma32(kf0, qf0, zed);                                              \
        sv = mfma32(kf1, qf1, sv);                                               \
        sv = mfma32(kf2, qf2, sv);                                               \
        sv = mfma32(kf3, qf3, sv);                                               \
        __builtin_amdgcn_s_setprio(0);                                           \
        if (kb0 + 31 > qminw) {                                                  \
            _Pragma("unroll") for (int r = 0; r < 16; r++) {                     \
                int kvg = kb0 + (r & 3) + 8 * (r >> 2) + 4 * hi;                 \
                float pv = __builtin_amdgcn_rcpf(1.f + exp2_hw(sv[r]));          \
                sv[r] = (kvg <= qrow) ? pv : 0.f;                                \
            }                                                                    \
        } else {                                                                 \
            _Pragma("unroll") for (int r = 0; r < 16; r++)                       \
                sv[r] = __builtin_amdgcn_rcpf(1.f + exp2_hw(sv[r]));             \
        }                                                                        \
        _Pragma("unroll") for (int k2 = 0; k2 < 2; k2++) {                       \
            unsigned wA = cvt_pk_bf16(sv[8 * k2 + 0], sv[8 * k2 + 1]);           \
            unsigned wC = cvt_pk_bf16(sv[8 * k2 + 2], sv[8 * k2 + 3]);           \
            unsigned wB = cvt_pk_bf16(sv[8 * k2 + 4], sv[8 * k2 + 5]);           \
            unsigned wD = cvt_pk_bf16(sv[8 * k2 + 6], sv[8 * k2 + 7]);           \
            plane_swap(wA, wB);                                                  \
            plane_swap(wC, wD);                                                  \
            union { unsigned u[4]; bf16x8 v; } pw;                               \
            pw.u[0] = wA; pw.u[1] = wC; pw.u[2] = wB; pw.u[3] = wD;              \
            __builtin_amdgcn_s_setprio(1);                                       \
            yac0 = mfma32(pw.v, k2 ? vf01 : vf00, yac0);                         \
            yac1 = mfma32(pw.v, k2 ? vf11 : vf10, yac1);                         \
            __builtin_amdgcn_s_setprio(0);                                       \
        }                                                                        \
    }                                                                            \
    asm volatile("" ::: "memory");                                               \
    if (++s >= ns) goto eplg;                                                    \
}

__global__ __launch_bounds__(256, 3) void attn20(
    const short* __restrict__ qn, const short* __restrict__ kn,
    const short* __restrict__ vt, short* __restrict__ yb)
{
    __shared__ alignas(16) char Smem[49152];   // K 3x8K | V 3x8K; Yred overlay

    int id = blockIdx.x;
    int h  = id & 15;
    int g  = id >> 4;                                // 0..63
    int t  = (g < 16) ? (63 - g) : (g < 32) ? (g - 16)
           : (g < 48) ? (79 - g) : (g - 32);         // per-CU quadruple sums const
    int ns = t + 1;                                  // 64-kv steps

    int tid = threadIdx.x, wv = tid >> 6, lane = tid & 63;
    int lo = lane & 31, hi = lane >> 5;
    int band = wv & 1, tm = wv >> 1;

    const short* Qh = qn + (size_t)h * T_SEQ * HEAD_DIM;
    const short* Kh = kn + (size_t)h * T_SEQ * HEAD_DIM;
    const short* Vh = vt + (size_t)h * HEAD_DIM * T_SEQ;

    int q0 = t * 64;
    int qrow  = q0 + band * 32 + lo;
    int qminw = q0 + band * 32;
    int qmaxw = q0 + band * 32 + 31;

    const short* Qr = &Qh[(size_t)qrow * HEAD_DIM + hi * 8];
    bf16x8 qf0 = *(const bf16x8*)&Qr[0];
    bf16x8 qf1 = *(const bf16x8*)&Qr[16];
    bf16x8 qf2 = *(const bf16x8*)&Qr[32];
    bf16x8 qf3 = *(const bf16x8*)&Qr[48];

    f32x16 zed;
#pragma unroll
    for (int r = 0; r < 16; r++) zed[r] = 0.f;

    f32x16 yac0, yac1;
#pragma unroll
    for (int r = 0; r < 16; r++) { yac0[r] = 0.f; yac1[r] = 0.f; }

    // loop-invariant LDS byte offsets (swizzled reads; relative to buffer bases)
    unsigned sw   = (unsigned)((lo & 7) << 4);
    unsigned krow = (unsigned)((tm * 32 + lo) * 128);
    unsigned ko0 = krow + ((0u * 32 + hi * 16) ^ sw);
    unsigned ko1 = krow + ((1u * 32 + hi * 16) ^ sw);
    unsigned ko2 = krow + ((2u * 32 + hi * 16) ^ sw);
    unsigned ko3 = krow + ((3u * 32 + hi * 16) ^ sw);
    unsigned vrow0 = (unsigned)(lo * 128);
    unsigned vrow1 = (unsigned)((32 + lo) * 128);
    unsigned vo00 = vrow0 + (((unsigned)(tm * 64 + 0 * 32 + hi * 16)) ^ sw);
    unsigned vo01 = vrow0 + (((unsigned)(tm * 64 + 1 * 32 + hi * 16)) ^ sw);
    unsigned vo10 = vrow1 + (((unsigned)(tm * 64 + 0 * 32 + hi * 16)) ^ sw);
    unsigned vo11 = vrow1 + (((unsigned)(tm * 64 + 1 * 32 + hi * 16)) ^ sw);

    // prologue: stage steps 0 and 1 (stage(1) reads in-bounds rows even if ns==1)
    STAGE20(0, 0);
    STAGE20(1, 1);

    {
        int s = 0;
        while (true) {
            ASTEP(0, 2);
            ASTEP(1, 0);
            ASTEP(2, 1);
        }
    }
eplg:

    // ---- cross-team reduce (kv halves) + store ----
    __syncthreads();
    float* Yred = (float*)Smem;                      // [2 band][32 q][64 d] overlay
    if (tm == 1) {
#pragma unroll
        for (int d = 0; d < 2; d++)
#pragma unroll
            for (int r = 0; r < 16; r++) {
                int crow = (r & 3) + 8 * (r >> 2) + 4 * hi;
                Yred[(band * 32 + crow) * 64 + d * 32 + lo] = d ? yac1[r] : yac0[r];
            }
    }
    __syncthreads();
    if (tm == 0) {
#pragma unroll
        for (int d = 0; d < 2; d++)
#pragma unroll
            for (int r = 0; r < 16; r++) {
                int crow = (r & 3) + 8 * (r >> 2) + 4 * hi;
                float v = (d ? yac1[r] : yac0[r]) + Yred[(band * 32 + crow) * 64 + d * 32 + lo];
                yb[(size_t)(q0 + band * 32 + crow) * C_DIM + h * HEAD_DIM + d * 32 + lo] = f2bf(v);
            }
    }
}

// ---------- launch ----------
extern "C" void kernel_launch(void* const* d_in, const int* in_sizes, int n_in,
                              void* d_out, int out_size, void* d_ws, size_t ws_size,
                              hipStream_t stream)
{
    const float* x    = (const float*)d_in[0];
    const float* cosT = (const float*)d_in[1];
    const float* sinT = (const float*)d_in[2];
    const float* wq   = (const float*)d_in[3];
    const float* wk   = (const float*)d_in[4];
    const float* wv   = (const float*)d_in[5];
    const float* wp   = (const float*)d_in[6];

    char* ws = (char*)d_ws;
    const size_t MB = 1024 * 1024;
    short* xb    = (short*)(ws + 0);        // [4096][1024] bf16   8 MiB
    short* wqb   = (short*)(ws + 8  * MB);
    short* wkb   = (short*)(ws + 10 * MB);
    short* wvb   = (short*)(ws + 12 * MB);
    short* wpb   = (short*)(ws + 14 * MB);  // pre-scaled by INV64
    short* qnb   = (short*)(ws + 16 * MB);  // [16][4096][64] bf16 8 MiB
    short* knb   = (short*)(ws + 24 * MB);
    short* vtb   = (short*)(ws + 32 * MB);  // [16][64][4096] bf16 8 MiB (direct)
    short* yb    = (short*)(ws + 40 * MB);  // [4096][1024] bf16   8 MiB

    // 1. cast inputs to bf16 (wproj scaled by INV64)
    cast5<<<dim3(4096, 5, 1), 256, 0, stream>>>(
        x, wq, wk, wv, wp, xb, wqb, wkb, wvb, wpb,
        T_SEQ * C_DIM, C_DIM * C_DIM, C_DIM * C_DIM, C_DIM * C_DIM, C_DIM * C_DIM);

    // 2. fused QKV GEMM + RoPE/RMS (q,k) + direct V-transpose (vtrans fused)
    gemm_qkv<<<dim3(24, 32, 1), 256, 0, stream>>>(
        xb, wqb, wkb, wvb, qnb, knb, vtb, cosT, sinT);

    // 3. causal sigmoid attention (3-buffer single-barrier pipeline)
    attn20<<<1024, 256, 0, stream>>>(qnb, knb, vtb, yb);

    // 4. output projection (fp32 out, col-fast grid)
    gemm_proj<<<dim3(8, 32, 1), 256, 0, stream>>>(
        yb, wpb, (float*)d_out, T_SEQ, C_DIM, C_DIM);
}